// Round 1
// baseline (256.519 us; speedup 1.0000x reference)
//
#include <hip/hip_runtime.h>
#include <math.h>

#define N 512
#define NN (N * N)
#define C 16
#define K 262144
#define LOG2N 9
#define NCOL 8

// skewed LDS addressing for the FFT arrays (float2-element units): +1 every 16
// elements. Makes the stride-2^s butterfly access patterns hit the b64
// bank-floor (4 words/bank) instead of 8-16-way conflicts.
#define SK(e) ((e) + ((e) >> 4))
#define LROW 544   // 512 + 32 skew slack

// ============ phase 1: bin points by cell (counting sort, no fp atomics) ============

__global__ __launch_bounds__(256) void prep_hist_kernel(const float2* __restrict__ traj,
                                                        const float* __restrict__ dcf,
                                                        int* __restrict__ cell,
                                                        float* __restrict__ sdcf,
                                                        int* __restrict__ count) {
    int k = blockIdx.x * 256 + threadIdx.x;
    float2 t = traj[k];
    int iy = __float2int_rn((t.x + 0.5f) * (float)N) & (N - 1);
    int ix = __float2int_rn((t.y + 0.5f) * (float)N) & (N - 1);
    int cl = iy * N + ix;
    cell[k] = cl;
    float s = ((iy + ix) & 1) ? -1.0f : 1.0f;   // ifftshift folded into input sign
    sdcf[k] = dcf[k] * s;
    atomicAdd(&count[cl], 1);
}

__global__ __launch_bounds__(256) void scan_reduce_kernel(const int* __restrict__ count,
                                                          int* __restrict__ bsum) {
    __shared__ int sd[256];
    int t = threadIdx.x;
    const int4* c4 = (const int4*)count;
    int4 v = c4[blockIdx.x * 256 + t];
    sd[t] = v.x + v.y + v.z + v.w;
    __syncthreads();
    for (int d = 128; d > 0; d >>= 1) {
        if (t < d) sd[t] += sd[t + d];
        __syncthreads();
    }
    if (t == 0) bsum[blockIdx.x] = sd[0];
}

__global__ __launch_bounds__(256) void scan_top_kernel(const int* __restrict__ bsum,
                                                       int* __restrict__ boffs,
                                                       int* __restrict__ offs) {
    __shared__ int sd[256];
    int t = threadIdx.x;
    int v = bsum[t];
    sd[t] = v;
    __syncthreads();
    for (int d = 1; d < 256; d <<= 1) {
        int tmp = (t >= d) ? sd[t - d] : 0;
        __syncthreads();
        sd[t] += tmp;
        __syncthreads();
    }
    boffs[t] = sd[t] - v;
    if (t == 0) offs[NN] = K;
}

__global__ __launch_bounds__(256) void scan_final_kernel(const int* __restrict__ count,
                                                         const int* __restrict__ boffs,
                                                         int* __restrict__ offs,
                                                         int* __restrict__ cursor) {
    __shared__ int sd[256];
    int t = threadIdx.x;
    int base_idx = blockIdx.x * 256 + t;
    const int4* c4 = (const int4*)count;
    int4 v = c4[base_idx];
    int s = v.x + v.y + v.z + v.w;
    sd[t] = s;
    __syncthreads();
    for (int d = 1; d < 256; d <<= 1) {
        int tmp = (t >= d) ? sd[t - d] : 0;
        __syncthreads();
        sd[t] += tmp;
        __syncthreads();
    }
    int base = boffs[blockIdx.x] + sd[t] - s;
    int4 o;
    o.x = base;
    o.y = base + v.x;
    o.z = base + v.x + v.y;
    o.w = base + v.x + v.y + v.z;
    ((int4*)offs)[base_idx] = o;
    ((int4*)cursor)[base_idx] = o;
}

// ============ payload build: transpose x to sorted point order ============
// Reads x COALESCED (k fast axis), transposes 256pt x 16ch tiles through LDS,
// writes per-point all-channel payloads (64 B chunks) at the sorted slot p.
// All randomness confined to full-line 64-B writes; build8 then reads
// payloads fully sequentially.
__global__ __launch_bounds__(256) void payload_kernel(const float* __restrict__ xr,
                                                      const float* __restrict__ xi,
                                                      const int* __restrict__ cell,
                                                      const float* __restrict__ sdcf,
                                                      int* __restrict__ cursor,
                                                      float2* __restrict__ payA,
                                                      float2* __restrict__ payB,
                                                      unsigned short* __restrict__ colv) {
    __shared__ float tR[256][17];   // [point][channel], +1 pad -> conflict-free
    __shared__ float tI[256][17];
    __shared__ int   sp[256];
    __shared__ float sw[256];
    int t = threadIdx.x;
    int k0 = blockIdx.x * 256;
#pragma unroll
    for (int c = 0; c < C; ++c) {
        tR[t][c] = xr[(size_t)c * K + k0 + t];   // coalesced 1-KB reads
        tI[t][c] = xi[(size_t)c * K + k0 + t];
    }
    int cl = cell[k0 + t];
    float w = sdcf[k0 + t];
    int p = atomicAdd(&cursor[cl], 1);           // unique sorted slot
    colv[p] = (unsigned short)(cl & (N - 1));
    sp[t] = p;
    sw[t] = w;
    __syncthreads();
    int sg = t >> 3, l = t & 7;                  // 32 subgroups of 8 lanes
    for (int j = sg; j < 256; j += 32) {
        int pp = sp[j];
        float ww = sw[j];
        // 8 lanes write one contiguous 64-B chunk per payload half
        payA[(size_t)pp * 8 + l] = make_float2(tR[j][l] * ww,     tI[j][l] * ww);
        payB[(size_t)pp * 8 + l] = make_float2(tR[j][8 + l] * ww, tI[j][8 + l] * ww);
    }
}

// ============ fused grid-build + row FFT, 8 channels/block ============
// block = (row r, channel-half h). Payload reads are CONTIGUOUS (points of
// row r are consecutive in sorted order): zero random global access.
// FFT: one sincos per thread per stage, reused across 8 channels; skewed
// float2 LDS layout -> butterfly LDS ops at the bank floor.
__global__ __launch_bounds__(256) void build8_kernel(const int* __restrict__ offs,
                                                     const float2* __restrict__ payA,
                                                     const float2* __restrict__ payB,
                                                     const unsigned short* __restrict__ colv,
                                                     float2* __restrict__ grid) {
    __shared__ float2 lds[8][LROW];   // 34.8 KB -> 4 blocks/CU
    int bid = blockIdx.x;
    int h = bid & 1;
    int r = bid >> 1;
    int t = threadIdx.x;
    float2* flat = &lds[0][0];
    for (int i = t; i < 8 * LROW; i += 256) flat[i] = make_float2(0.f, 0.f);
    int start = offs[r * N];
    int end   = offs[r * N + N];      // r=511 uses offs[NN]=K
    const float2* pay = h ? payB : payA;
    __syncthreads();

    // sequential payload read: lane-consecutive 64-B chunks, 4x dwordx4/point
    for (int p = start + t; p < end; p += 256) {
        int col = colv[p];
        int bc = (int)(__brev((unsigned)col) >> (32 - LOG2N));  // bit-reversed col
        const float4* pp = (const float4*)(pay + (size_t)p * 8);
        float4 q0 = pp[0], q1 = pp[1], q2 = pp[2], q3 = pp[3];
        int a = SK(bc);
        atomicAdd(&lds[0][a].x, q0.x); atomicAdd(&lds[0][a].y, q0.y);
        atomicAdd(&lds[1][a].x, q0.z); atomicAdd(&lds[1][a].y, q0.w);
        atomicAdd(&lds[2][a].x, q1.x); atomicAdd(&lds[2][a].y, q1.y);
        atomicAdd(&lds[3][a].x, q1.z); atomicAdd(&lds[3][a].y, q1.w);
        atomicAdd(&lds[4][a].x, q2.x); atomicAdd(&lds[4][a].y, q2.y);
        atomicAdd(&lds[5][a].x, q2.z); atomicAdd(&lds[5][a].y, q2.w);
        atomicAdd(&lds[6][a].x, q3.x); atomicAdd(&lds[6][a].y, q3.y);
        atomicAdd(&lds[7][a].x, q3.z); atomicAdd(&lds[7][a].y, q3.w);
    }
    __syncthreads();

    // 9 radix-2 DIT stages, +i exponent; input bit-reversed, output natural
    for (int s = 1; s <= LOG2N; ++s) {
        int half = 1 << (s - 1);
        int m = half << 1;
        int j = t & (half - 1);
        int grp = t >> (s - 1);
        int p1 = grp * m + j;
        int p2 = p1 + half;
        float ang = 6.283185307179586f * (float)j / (float)m;
        float sn, cs;
        __sincosf(ang, &sn, &cs);
        int a1 = SK(p1), a2 = SK(p2);
#pragma unroll
        for (int c = 0; c < 8; ++c) {
            float2 v = lds[c][a2];
            float tr = cs * v.x - sn * v.y;
            float ti = cs * v.y + sn * v.x;
            float2 u = lds[c][a1];
            lds[c][a2] = make_float2(u.x - tr, u.y - ti);
            lds[c][a1] = make_float2(u.x + tr, u.y + ti);
        }
        __syncthreads();
    }

    int c0 = h * 8;
#pragma unroll
    for (int c = 0; c < 8; ++c) {
        float2* g = grid + (size_t)(c0 + c) * NN + (size_t)r * N;
        for (int i = t; i < N; i += 256) g[i] = lds[c][SK(i)];
    }
}

// ============ column FFT: NCOL columns per block through LDS ============
__global__ __launch_bounds__(256) void colfft_kernel(float2* __restrict__ grid) {
    __shared__ float sr[N * NCOL];
    __shared__ float si[N * NCOL];
    int blk = blockIdx.x;                        // c * (N/NCOL) + cg
    int c = blk >> 6;
    int cg = blk & 63;
    float2* base = grid + (size_t)c * NN + cg * NCOL;
    int t = threadIdx.x;

    for (int e = t; e < N * NCOL; e += 256) {
        int row = e >> 3, col = e & 7;
        float2 v = base[(size_t)row * N + col];
        sr[e] = v.x; si[e] = v.y;
    }
    __syncthreads();

    int col = t & 7;
    int tg = t >> 3;
    for (int i = tg; i < N; i += 32) {
        int j = __brev((unsigned)i) >> (32 - LOG2N);
        if (j > i) {
            int a1 = i * NCOL + col, a2 = j * NCOL + col;
            float a = sr[a1]; sr[a1] = sr[a2]; sr[a2] = a;
            float b = si[a1]; si[a1] = si[a2]; si[a2] = b;
        }
    }
    __syncthreads();

    for (int s = 1; s <= LOG2N; ++s) {
        int half = 1 << (s - 1);
        int m = half << 1;
        for (int b = tg; b < 256; b += 32) {
            int j = b & (half - 1);
            int grp = b >> (s - 1);
            int p1 = grp * m + j;
            int p2 = p1 + half;
            float ang = 6.283185307179586f * (float)j / (float)m;
            float sn, cs;
            __sincosf(ang, &sn, &cs);
            int a1 = p1 * NCOL + col, a2 = p2 * NCOL + col;
            float xr2 = sr[a2], xi2 = si[a2];
            float tr = cs * xr2 - sn * xi2;
            float ti = cs * xi2 + sn * xr2;
            float ur = sr[a1], ui = si[a1];
            sr[a2] = ur - tr; si[a2] = ui - ti;
            sr[a1] = ur + tr; si[a1] = ui + ti;
        }
        __syncthreads();
    }

    for (int e = t; e < N * NCOL; e += 256) {
        int row = e >> 3, col2 = e & 7;
        base[(size_t)row * N + col2] = make_float2(sr[e], si[e]);
    }
}

// ============ combine: out = (-1)^(ny+nx) * sum_c conj(csm)*img ============
__global__ __launch_bounds__(256) void combine_kernel(const float* __restrict__ csr,
                                                      const float* __restrict__ csi,
                                                      const float2* __restrict__ grid,
                                                      float* __restrict__ out) {
    int pix = blockIdx.x * 256 + threadIdx.x;
    int ny = pix >> LOG2N, nx = pix & (N - 1);
    float ar = 0.f, ai = 0.f;
#pragma unroll
    for (int c = 0; c < C; ++c) {
        float2 uv = grid[(size_t)c * NN + pix];
        float a = csr[c * NN + pix];
        float b = csi[c * NN + pix];
        ar += a * uv.x + b * uv.y;
        ai += a * uv.y - b * uv.x;
    }
    float s = ((ny + nx) & 1) ? -1.f : 1.f;      // fftshift folded into output sign
    out[pix] = s * ar;
    out[NN + pix] = s * ai;
}

extern "C" void kernel_launch(void* const* d_in, const int* in_sizes, int n_in,
                              void* d_out, int out_size, void* d_ws, size_t ws_size,
                              hipStream_t stream) {
    const float* x_real   = (const float*)d_in[0];
    const float* x_imag   = (const float*)d_in[1];
    const float* csm_real = (const float*)d_in[2];
    const float* csm_imag = (const float*)d_in[3];
    const float2* traj    = (const float2*)d_in[4];
    const float* dcf      = (const float*)d_in[5];
    float* out = (float*)d_out;

    char* ws = (char*)d_ws;
    size_t o = 0;
    float* grid  = (float*)(ws + o); o += (size_t)C * NN * 2 * sizeof(float);  // 32 MB
    int*   cell  = (int*)(ws + o);   o += (size_t)K * sizeof(int);             // 1 MB
    float* sdcf  = (float*)(ws + o); o += (size_t)K * sizeof(float);           // 1 MB
    int*   count = (int*)(ws + o);   o += (size_t)NN * sizeof(int);            // 1 MB
    int*   offs  = (int*)(ws + o);   o += ((size_t)NN + 4) * sizeof(int);      // 1 MB (+pad)
    int*   cursor= (int*)(ws + o);   o += (size_t)NN * sizeof(int);            // 1 MB
    float2* payA = (float2*)(ws + o); o += (size_t)K * 8 * sizeof(float2);     // 16 MB
    float2* payB = (float2*)(ws + o); o += (size_t)K * 8 * sizeof(float2);     // 16 MB
    unsigned short* colv = (unsigned short*)(ws + o); o += (size_t)K * sizeof(unsigned short); // 0.5 MB
    int*   bsum  = (int*)(ws + o);   o += 256 * sizeof(int);
    int*   boffs = (int*)(ws + o);   o += 256 * sizeof(int);

    (void)hipMemsetAsync(count, 0, (size_t)NN * sizeof(int), stream);

    prep_hist_kernel<<<K / 256, 256, 0, stream>>>(traj, dcf, cell, sdcf, count);
    scan_reduce_kernel<<<256, 256, 0, stream>>>(count, bsum);
    scan_top_kernel<<<1, 256, 0, stream>>>(bsum, boffs, offs);
    scan_final_kernel<<<256, 256, 0, stream>>>(count, boffs, offs, cursor);
    payload_kernel<<<K / 256, 256, 0, stream>>>(x_real, x_imag, cell, sdcf, cursor, payA, payB, colv);
    build8_kernel<<<N * 2, 256, 0, stream>>>(offs, payA, payB, colv, (float2*)grid);
    colfft_kernel<<<C * (N / NCOL), 256, 0, stream>>>((float2*)grid);
    combine_kernel<<<NN / 256, 256, 0, stream>>>(csm_real, csm_imag, (float2*)grid, out);
}

// Round 2
// 215.892 us; speedup vs baseline: 1.1882x; 1.1882x over previous
//
#include <hip/hip_runtime.h>
#include <math.h>

#define N 512
#define NN (N * N)
#define C 16
#define K 262144
#define LOG2N 9
#define NCOL 8

// skewed LDS addressing (float4-element units): +1 every 16 elements.
// Makes bit-reversed scatter writes and stride-2^s butterfly b128 accesses
// hit the LDS byte floor (8 cycles / KB) instead of 8-16-way conflicts.
#define SK(e) ((e) + ((e) >> 4))
#define LROW 544   // 512 + 32 skew slack

// ============ phase 1: bin points by cell (counting sort, no fp atomics) ============

__global__ __launch_bounds__(256) void prep_hist_kernel(const float2* __restrict__ traj,
                                                        const float* __restrict__ dcf,
                                                        int* __restrict__ cell,
                                                        float* __restrict__ sdcf,
                                                        int* __restrict__ count) {
    int k = blockIdx.x * 256 + threadIdx.x;
    float2 t = traj[k];
    int iy = __float2int_rn((t.x + 0.5f) * (float)N) & (N - 1);
    int ix = __float2int_rn((t.y + 0.5f) * (float)N) & (N - 1);
    int cl = iy * N + ix;
    cell[k] = cl;
    float s = ((iy + ix) & 1) ? -1.0f : 1.0f;   // ifftshift folded into input sign
    sdcf[k] = dcf[k] * s;
    atomicAdd(&count[cl], 1);
}

__global__ __launch_bounds__(256) void scan_reduce_kernel(const int* __restrict__ count,
                                                          int* __restrict__ bsum) {
    __shared__ int sd[256];
    int t = threadIdx.x;
    const int4* c4 = (const int4*)count;
    int4 v = c4[blockIdx.x * 256 + t];
    sd[t] = v.x + v.y + v.z + v.w;
    __syncthreads();
    for (int d = 128; d > 0; d >>= 1) {
        if (t < d) sd[t] += sd[t + d];
        __syncthreads();
    }
    if (t == 0) bsum[blockIdx.x] = sd[0];
}

__global__ __launch_bounds__(256) void scan_top_kernel(const int* __restrict__ bsum,
                                                       int* __restrict__ boffs,
                                                       int* __restrict__ offs) {
    __shared__ int sd[256];
    int t = threadIdx.x;
    int v = bsum[t];
    sd[t] = v;
    __syncthreads();
    for (int d = 1; d < 256; d <<= 1) {
        int tmp = (t >= d) ? sd[t - d] : 0;
        __syncthreads();
        sd[t] += tmp;
        __syncthreads();
    }
    boffs[t] = sd[t] - v;
    if (t == 0) offs[NN] = K;
}

__global__ __launch_bounds__(256) void scan_final_kernel(const int* __restrict__ count,
                                                         const int* __restrict__ boffs,
                                                         int* __restrict__ offs,
                                                         int* __restrict__ cursor) {
    __shared__ int sd[256];
    int t = threadIdx.x;
    int base_idx = blockIdx.x * 256 + t;
    const int4* c4 = (const int4*)count;
    int4 v = c4[base_idx];
    int s = v.x + v.y + v.z + v.w;
    sd[t] = s;
    __syncthreads();
    for (int d = 1; d < 256; d <<= 1) {
        int tmp = (t >= d) ? sd[t - d] : 0;
        __syncthreads();
        sd[t] += tmp;
        __syncthreads();
    }
    int base = boffs[blockIdx.x] + sd[t] - s;
    int4 o;
    o.x = base;
    o.y = base + v.x;
    o.z = base + v.x + v.y;
    o.w = base + v.x + v.y + v.z;
    ((int4*)offs)[base_idx] = o;
    ((int4*)cursor)[base_idx] = o;
}

// ============ payload build: transpose x to sorted point order ============
// Reads x COALESCED (k fast axis), transposes 256pt x 16ch tiles through LDS,
// writes per-point all-channel payloads (64 B chunks) at the sorted slot p.
__global__ __launch_bounds__(256) void payload_kernel(const float* __restrict__ xr,
                                                      const float* __restrict__ xi,
                                                      const int* __restrict__ cell,
                                                      const float* __restrict__ sdcf,
                                                      int* __restrict__ cursor,
                                                      float2* __restrict__ payA,
                                                      float2* __restrict__ payB) {
    __shared__ float tR[256][17];   // [point][channel], +1 pad -> conflict-free
    __shared__ float tI[256][17];
    __shared__ int   sp[256];
    __shared__ float sw[256];
    int t = threadIdx.x;
    int k0 = blockIdx.x * 256;
#pragma unroll
    for (int c = 0; c < C; ++c) {
        tR[t][c] = xr[(size_t)c * K + k0 + t];   // coalesced 1-KB reads
        tI[t][c] = xi[(size_t)c * K + k0 + t];
    }
    int cl = cell[k0 + t];
    float w = sdcf[k0 + t];
    int p = atomicAdd(&cursor[cl], 1);           // unique sorted slot
    sp[t] = p;
    sw[t] = w;
    __syncthreads();
    int sg = t >> 3, l = t & 7;                  // 32 subgroups of 8 lanes
    for (int j = sg; j < 256; j += 32) {
        int pp = sp[j];
        float ww = sw[j];
        // 8 lanes write one contiguous 64-B chunk per payload half
        payA[(size_t)pp * 8 + l] = make_float2(tR[j][l] * ww,     tI[j][l] * ww);
        payB[(size_t)pp * 8 + l] = make_float2(tR[j][8 + l] * ww, tI[j][8 + l] * ww);
    }
}

// ============ fused grid-build + row FFT: atomic-free, barrier-free ============
// block = (row r, channel-half h), 4 waves. Wave w owns channels {2w,2w+1} of
// its half: a private float4 LDS stripe. Gather is CELL-parallel: each lane
// owns 8 cells; points of a cell are consecutive in sorted order -> register
// accumulate + ONE plain ds_write_b128 per cell (no LDS atomics, no zero-init).
// FFT is wave-local: stage ordering via s_waitcnt lgkmcnt(0) (drains this
// wave's own DS queue -> hard completion guarantee). ZERO __syncthreads.
__global__ __launch_bounds__(256) void build8_kernel(const int* __restrict__ offs,
                                                     const float4* __restrict__ payA4,
                                                     const float4* __restrict__ payB4,
                                                     float2* __restrict__ grid) {
    __shared__ float4 lds[4][LROW];   // 34.8 KB -> 4 blocks/CU
    int bid = blockIdx.x;
    int h = bid & 1;
    int r = bid >> 1;
    int t = threadIdx.x;
    int w = t >> 6;                   // wave id 0..3 -> channels h*8+2w, h*8+2w+1
    int l = t & 63;
    const float4* pay = h ? payB4 : payA4;   // point p = [p*4 .. p*4+3]; wave reads p*4+w
    const int* ro = offs + r * N;

    // ---- gather: 8 cells per lane, register accumulate, one b128 write each ----
#pragma unroll
    for (int it = 0; it < 8; ++it) {
        int col = l + (it << 6);
        int s = ro[col];
        int e = ro[col + 1];          // col=511 reads offs[(r+1)*N]; r=511 -> offs[NN]=K
        float4 acc = make_float4(0.f, 0.f, 0.f, 0.f);
        for (int p = s; p < e; ++p) { // avg 1 point/cell
            float4 v = pay[(size_t)p * 4 + w];
            acc.x += v.x; acc.y += v.y; acc.z += v.z; acc.w += v.w;
        }
        int bc = (int)(__brev((unsigned)col) >> (32 - LOG2N));   // bit-reversed col
        lds[w][SK(bc)] = acc;
    }
    asm volatile("s_waitcnt lgkmcnt(0)" ::: "memory");

    // ---- 9 radix-2 DIT stages, +i exponent, wave-local (no barriers) ----
    for (int s = 1; s <= LOG2N; ++s) {
        int half = 1 << (s - 1);
        int m = half << 1;
#pragma unroll
        for (int i = 0; i < 4; ++i) {          // 256 butterflies / 64 lanes
            int b = l + (i << 6);
            int j = b & (half - 1);
            int grp = b >> (s - 1);
            int p1 = grp * m + j;
            int p2 = p1 + half;
            float ang = 6.283185307179586f * (float)j / (float)m;
            float sn, cs;
            __sincosf(ang, &sn, &cs);
            float4 v = lds[w][SK(p2)];
            float4 u = lds[w][SK(p1)];
            float tr0 = cs * v.x - sn * v.y;
            float ti0 = cs * v.y + sn * v.x;
            float tr1 = cs * v.z - sn * v.w;
            float ti1 = cs * v.w + sn * v.z;
            lds[w][SK(p2)] = make_float4(u.x - tr0, u.y - ti0, u.z - tr1, u.w - ti1);
            lds[w][SK(p1)] = make_float4(u.x + tr0, u.y + ti0, u.z + tr1, u.w + ti1);
        }
        asm volatile("s_waitcnt lgkmcnt(0)" ::: "memory");
    }

    // ---- store this wave's 2 channels, coalesced ----
    int c0 = h * 8 + (w << 1);
    float2* g0 = grid + (size_t)c0 * NN + (size_t)r * N;
    float2* g1 = grid + (size_t)(c0 + 1) * NN + (size_t)r * N;
    for (int i = l; i < N; i += 64) {
        float4 v = lds[w][SK(i)];
        g0[i] = make_float2(v.x, v.y);
        g1[i] = make_float2(v.z, v.w);
    }
}

// ============ column FFT: NCOL columns per block through LDS ============
__global__ __launch_bounds__(256) void colfft_kernel(float2* __restrict__ grid) {
    __shared__ float sr[N * NCOL];
    __shared__ float si[N * NCOL];
    int blk = blockIdx.x;                        // c * (N/NCOL) + cg
    int c = blk >> 6;
    int cg = blk & 63;
    float2* base = grid + (size_t)c * NN + cg * NCOL;
    int t = threadIdx.x;

    for (int e = t; e < N * NCOL; e += 256) {
        int row = e >> 3, col = e & 7;
        float2 v = base[(size_t)row * N + col];
        sr[e] = v.x; si[e] = v.y;
    }
    __syncthreads();

    int col = t & 7;
    int tg = t >> 3;
    for (int i = tg; i < N; i += 32) {
        int j = __brev((unsigned)i) >> (32 - LOG2N);
        if (j > i) {
            int a1 = i * NCOL + col, a2 = j * NCOL + col;
            float a = sr[a1]; sr[a1] = sr[a2]; sr[a2] = a;
            float b = si[a1]; si[a1] = si[a2]; si[a2] = b;
        }
    }
    __syncthreads();

    for (int s = 1; s <= LOG2N; ++s) {
        int half = 1 << (s - 1);
        int m = half << 1;
        for (int b = tg; b < 256; b += 32) {
            int j = b & (half - 1);
            int grp = b >> (s - 1);
            int p1 = grp * m + j;
            int p2 = p1 + half;
            float ang = 6.283185307179586f * (float)j / (float)m;
            float sn, cs;
            __sincosf(ang, &sn, &cs);
            int a1 = p1 * NCOL + col, a2 = p2 * NCOL + col;
            float xr2 = sr[a2], xi2 = si[a2];
            float tr = cs * xr2 - sn * xi2;
            float ti = cs * xi2 + sn * xr2;
            float ur = sr[a1], ui = si[a1];
            sr[a2] = ur - tr; si[a2] = ui - ti;
            sr[a1] = ur + tr; si[a1] = ui + ti;
        }
        __syncthreads();
    }

    for (int e = t; e < N * NCOL; e += 256) {
        int row = e >> 3, col2 = e & 7;
        base[(size_t)row * N + col2] = make_float2(sr[e], si[e]);
    }
}

// ============ combine: out = (-1)^(ny+nx) * sum_c conj(csm)*img ============
__global__ __launch_bounds__(256) void combine_kernel(const float* __restrict__ csr,
                                                      const float* __restrict__ csi,
                                                      const float2* __restrict__ grid,
                                                      float* __restrict__ out) {
    int pix = blockIdx.x * 256 + threadIdx.x;
    int ny = pix >> LOG2N, nx = pix & (N - 1);
    float ar = 0.f, ai = 0.f;
#pragma unroll
    for (int c = 0; c < C; ++c) {
        float2 uv = grid[(size_t)c * NN + pix];
        float a = csr[c * NN + pix];
        float b = csi[c * NN + pix];
        ar += a * uv.x + b * uv.y;
        ai += a * uv.y - b * uv.x;
    }
    float s = ((ny + nx) & 1) ? -1.f : 1.f;      // fftshift folded into output sign
    out[pix] = s * ar;
    out[NN + pix] = s * ai;
}

extern "C" void kernel_launch(void* const* d_in, const int* in_sizes, int n_in,
                              void* d_out, int out_size, void* d_ws, size_t ws_size,
                              hipStream_t stream) {
    const float* x_real   = (const float*)d_in[0];
    const float* x_imag   = (const float*)d_in[1];
    const float* csm_real = (const float*)d_in[2];
    const float* csm_imag = (const float*)d_in[3];
    const float2* traj    = (const float2*)d_in[4];
    const float* dcf      = (const float*)d_in[5];
    float* out = (float*)d_out;

    char* ws = (char*)d_ws;
    size_t o = 0;
    float* grid  = (float*)(ws + o); o += (size_t)C * NN * 2 * sizeof(float);  // 32 MB
    int*   cell  = (int*)(ws + o);   o += (size_t)K * sizeof(int);             // 1 MB
    float* sdcf  = (float*)(ws + o); o += (size_t)K * sizeof(float);           // 1 MB
    int*   count = (int*)(ws + o);   o += (size_t)NN * sizeof(int);            // 1 MB
    int*   offs  = (int*)(ws + o);   o += ((size_t)NN + 4) * sizeof(int);      // 1 MB (+pad)
    int*   cursor= (int*)(ws + o);   o += (size_t)NN * sizeof(int);            // 1 MB
    float2* payA = (float2*)(ws + o); o += (size_t)K * 8 * sizeof(float2);     // 16 MB
    float2* payB = (float2*)(ws + o); o += (size_t)K * 8 * sizeof(float2);     // 16 MB
    int*   bsum  = (int*)(ws + o);   o += 256 * sizeof(int);
    int*   boffs = (int*)(ws + o);   o += 256 * sizeof(int);

    (void)hipMemsetAsync(count, 0, (size_t)NN * sizeof(int), stream);

    prep_hist_kernel<<<K / 256, 256, 0, stream>>>(traj, dcf, cell, sdcf, count);
    scan_reduce_kernel<<<256, 256, 0, stream>>>(count, bsum);
    scan_top_kernel<<<1, 256, 0, stream>>>(bsum, boffs, offs);
    scan_final_kernel<<<256, 256, 0, stream>>>(count, boffs, offs, cursor);
    payload_kernel<<<K / 256, 256, 0, stream>>>(x_real, x_imag, cell, sdcf, cursor, payA, payB);
    build8_kernel<<<N * 2, 256, 0, stream>>>(offs, (const float4*)payA, (const float4*)payB, (float2*)grid);
    colfft_kernel<<<C * (N / NCOL), 256, 0, stream>>>((float2*)grid);
    combine_kernel<<<NN / 256, 256, 0, stream>>>(csm_real, csm_imag, (float2*)grid, out);
}